// Round 17
// baseline (164.577 us; speedup 1.0000x reference)
//
#include <hip/hip_runtime.h>
#include <hip/hip_bf16.h>

// ---------------------------------------------------------------------------
// Attention_58248346469030:  out = softmax((x@Wq)(x@Wk)^T * sc) @ (x@Wv) @ Wout + b
// B=4, S=2048, DIM=1024, INNER=1024 (full-dim attention, no head split).
//
// ALGEBRAIC FOLD (R10): dots = x@(sc*Wq@Wk^T)@x^T, out = (P@(x@(Wv@Wout)))/l + b
//   prep:  xh = fp16(x); WoutT = W_out^T fp16; prep_gemm64 (reads Wqkv f32
//          directly) -> Wyv [2048][1024] fp16
//   1) yv  = xh @ Wyv^T : y fp16 [8192][1024], v' bf16 -> VT[b][o][t]
//   2) P   = exp(y @ xh^T) bf16 + NON-ATOMIC per-wave rowsum partials
//            (shfl over fr-group, one plain store per (row,bx,wn) ->
//             rsum_p[z][row][32]; single producer per slot, no memset)
//   3) out = (P @ VT^T)/rowsum + bias; rowsum = LDS-staged reduction of the
//            32 partials per row (replaces R13's ones-MFMA: that cost +4.5us
//            of MFMA-pipe work; R12's atomics cost +7us in P).
//   T1 bijective XCD swizzle on all big GEMMs (FETCH 139->33MB).
// ---------------------------------------------------------------------------

typedef short    s16x8 __attribute__((ext_vector_type(8)));
typedef short    s16x4 __attribute__((ext_vector_type(4)));
typedef float    fx4   __attribute__((ext_vector_type(4)));
typedef _Float16 h16x8 __attribute__((ext_vector_type(8)));

__device__ __forceinline__ short f2bs(float f) {            // f32 -> bf16 bits (RNE)
  __hip_bfloat16 h = __float2bfloat16(f);
  short s; __builtin_memcpy(&s, &h, 2); return s;
}
__device__ __forceinline__ short f2hs(float f) {            // f32 -> fp16 bits (RNE)
  _Float16 h = (_Float16)f;
  short s; __builtin_memcpy(&s, &h, 2); return s;
}

__device__ __forceinline__ void gload16(const void* g, void* l) {
  __builtin_amdgcn_global_load_lds(
      (const __attribute__((address_space(1))) void*)g,
      (__attribute__((address_space(3))) void*)l, 16, 0, 0);
}

// T1: bijective XCD-chunked swizzle (grids all %8==0).
template<int GX, int GY>
__device__ __forceinline__ void xcd_map(int& bx, int& by, int& bz) {
  const int glin = ((int)blockIdx.z * GY + (int)blockIdx.y) * GX + (int)blockIdx.x;
  const int nwg  = GX * GY * (int)gridDim.z;
  const int s    = (glin & 7) * (nwg >> 3) + (glin >> 3);
  bx = s % GX;
  const int t = s / GX;
  by = t % GY;
  bz = t / GY;
}

// ---------------- prep kernels ----------------

__global__ void cvt_f32_f16(const float* __restrict__ in, short* __restrict__ out, int n4) {
  int i = blockIdx.x * blockDim.x + threadIdx.x;
  if (i < n4) {
    float4 v = reinterpret_cast<const float4*>(in)[i];
    s16x4 o;
    o.x = f2hs(v.x); o.y = f2hs(v.y); o.z = f2hs(v.z); o.w = f2hs(v.w);
    reinterpret_cast<s16x4*>(out)[i] = o;
  }
}

// WT[n][k] = W[k][n], fp16 out.
__global__ void transpose_w(const float* __restrict__ W, int K, int N,
                            short* __restrict__ WT) {
  __shared__ float tile[32][33];
  int k0 = blockIdx.y * 32, n0 = blockIdx.x * 32;
  int r = threadIdx.x >> 5, c = threadIdx.x & 31;
  for (int rr = r; rr < 32; rr += 8)
    tile[rr][c] = W[(size_t)(k0 + rr) * N + n0 + c];
  __syncthreads();
  for (int rr = r; rr < 32; rr += 8)
    WT[(size_t)(n0 + rr) * K + k0 + c] = f2hs(tile[c][rr]);
}

// Weight-fold GEMMs, 64x64 tiles, K=1024, fp16 MFMA. Reads Wqkv in f32
// (converted in-register during staging); A for the Wvo fold is WoutT fp16.
__global__ __launch_bounds__(256, 4)
void prep_gemm64(const float* __restrict__ Wqkv, const short* __restrict__ WoutT,
                 short* __restrict__ Wyv) {
  __shared__ __align__(16) short As[64 * 72];
  __shared__ __align__(16) short Bs[64 * 72];

  const bool isM = blockIdx.y < 16;
  const int arow0 = (blockIdx.y & 15) * 64;
  const int crow0 = arow0 + (isM ? 0 : 1024);
  const int bcol = blockIdx.x * 64;
  const float scale = isM ? 0.125f : 1.0f;

  const int t = threadIdx.x;
  const int r = t >> 2;
  const int sc = (t & 3) * 16;
  const float* Agf = Wqkv + (size_t)(arow0 + r) * 3072 + 1024 + sc;  // Wk f32
  const short* Agh = WoutT + (size_t)(arow0 + r) * 1024 + sc;        // WoutT fp16
  const float* Bgf = Wqkv + (size_t)(bcol + r) * 3072 + (isM ? 0 : 2048) + sc;

  short* Asw = &As[r * 72 + sc];
  short* Bsw = &Bs[r * 72 + sc];

  const int lane = t & 63;
  const int wid  = t >> 6;
  const int wm = wid >> 1, wn = wid & 1;
  const int fr = lane & 15, fg = lane >> 4;

  fx4 acc[2][2] = {};

  for (int kt = 0; kt < 1024; kt += 64) {
    s16x8 ar[2], br[2];
    if (isM) {
#pragma unroll
      for (int c = 0; c < 2; ++c) {
        float4 v0 = *reinterpret_cast<const float4*>(Agf + kt + c * 8);
        float4 v1 = *reinterpret_cast<const float4*>(Agf + kt + c * 8 + 4);
        ar[c][0] = f2hs(v0.x); ar[c][1] = f2hs(v0.y); ar[c][2] = f2hs(v0.z); ar[c][3] = f2hs(v0.w);
        ar[c][4] = f2hs(v1.x); ar[c][5] = f2hs(v1.y); ar[c][6] = f2hs(v1.z); ar[c][7] = f2hs(v1.w);
      }
    } else {
#pragma unroll
      for (int c = 0; c < 2; ++c)
        ar[c] = *reinterpret_cast<const s16x8*>(Agh + kt + c * 8);
    }
#pragma unroll
    for (int c = 0; c < 2; ++c) {
      float4 v0 = *reinterpret_cast<const float4*>(Bgf + kt + c * 8);
      float4 v1 = *reinterpret_cast<const float4*>(Bgf + kt + c * 8 + 4);
      br[c][0] = f2hs(v0.x); br[c][1] = f2hs(v0.y); br[c][2] = f2hs(v0.z); br[c][3] = f2hs(v0.w);
      br[c][4] = f2hs(v1.x); br[c][5] = f2hs(v1.y); br[c][6] = f2hs(v1.z); br[c][7] = f2hs(v1.w);
    }
    __syncthreads();
#pragma unroll
    for (int c = 0; c < 2; ++c) {
      *reinterpret_cast<s16x8*>(Asw + c * 8) = ar[c];
      *reinterpret_cast<s16x8*>(Bsw + c * 8) = br[c];
    }
    __syncthreads();
#pragma unroll
    for (int kk = 0; kk < 64; kk += 32) {
      s16x8 af[2], bf[2];
#pragma unroll
      for (int m = 0; m < 2; ++m)
        af[m] = *reinterpret_cast<const s16x8*>(&As[(wm * 32 + m * 16 + fr) * 72 + kk + fg * 8]);
#pragma unroll
      for (int n = 0; n < 2; ++n)
        bf[n] = *reinterpret_cast<const s16x8*>(&Bs[(wn * 32 + n * 16 + fr) * 72 + kk + fg * 8]);
#pragma unroll
      for (int m = 0; m < 2; ++m)
#pragma unroll
        for (int n = 0; n < 2; ++n)
          acc[m][n] = __builtin_amdgcn_mfma_f32_16x16x32_f16(
              __builtin_bit_cast(h16x8, af[m]), __builtin_bit_cast(h16x8, bf[n]),
              acc[m][n], 0, 0, 0);
    }
  }

  const int row0 = crow0 + wm * 32 + fg * 4;
  const int col0 = bcol + wn * 32 + fr;
#pragma unroll
  for (int m = 0; m < 2; ++m)
#pragma unroll
    for (int j = 0; j < 4; ++j) {
      const int row = row0 + m * 16 + j;
#pragma unroll
      for (int n = 0; n < 2; ++n)
        Wyv[(size_t)row * 1024 + col0 + n * 16] = f2hs(acc[m][n][j] * scale);
    }
}

// ---------------- 256x256 8-wave 4-slot ping-pong GEMM (R8 core + T1) ----------------
// C[M][N] = A[M][K] @ B'[N][K]^T
// EPI: 0 = yv write (cols <1024: y fp16; >=1024: v' bf16 -> VT=Cv2)
//      1 = exp -> bf16 + NON-ATOMIC rowsum partials -> auxw[z][row][32]
template<int EPI, int DT, int GX, int GY>
__global__ __launch_bounds__(512, 2)
void gemm256(const short* __restrict__ A, int lda, long long bsA,
             const short* __restrict__ B, int ldb, long long bsB,
             void* __restrict__ Cv, int ldc, long long bsC,
             int K, short* __restrict__ Cv2, float* __restrict__ auxw) {
  __shared__ __align__(16) short S[4][16384];

  const int t = threadIdx.x;
  int bx, by, z;
  xcd_map<GX, GY>(bx, by, z);
  A += (size_t)z * bsA;
  B += (size_t)z * bsB;

  const int brow = by * 256;
  const int bcol = bx * 256;

  const int lane = t & 63;
  const int wid  = t >> 6;
  const int wm = wid >> 2;
  const int wn = wid & 3;
  const int fr = lane & 15;
  const int fg = lane >> 4;

  const int l2 = lane >> 2;
  const int gsrc = ((lane & 3) ^ ((lane >> 3) & 3)) * 8;
  const short* Ag0 = A + (size_t)(brow + wid * 32 + l2) * lda + gsrc;
  const short* Ag1 = Ag0 + (size_t)16 * lda;
  const short* Bg0 = B + (size_t)(bcol + wid * 32 + l2) * ldb + gsrc;
  const short* Bg1 = Bg0 + (size_t)16 * ldb;
  const int dA = wid * 1024;
  const int dB = 8192 + wid * 1024;

  const int gq = (fg ^ ((fr >> 1) & 3)) * 8;
  const int aB = (wm * 128 + fr) * 32 + gq;
  const int bB = 8192 + (wn * 64 + fr) * 32 + gq;

  fx4 acc[8][4] = {};
  s16x8 ra[2][8], rb[2][4];
  const int Km32 = K - 32;

  auto MM = [&](s16x8 av, s16x8 bv, fx4 c) -> fx4 {
    if constexpr (DT == 0)
      return __builtin_amdgcn_mfma_f32_16x16x32_f16(
          __builtin_bit_cast(h16x8, av), __builtin_bit_cast(h16x8, bv), c, 0, 0, 0);
    else
      return __builtin_amdgcn_mfma_f32_16x16x32_bf16(av, bv, c, 0, 0, 0);
  };

#pragma unroll
  for (int s = 0; s < 3; ++s) {
    const int kk = s * 32;
    gload16(Ag0 + kk, &S[s][dA]);
    gload16(Ag1 + kk, &S[s][dA + 512]);
    gload16(Bg0 + kk, &S[s][dB]);
    gload16(Bg1 + kk, &S[s][dB + 512]);
  }
  asm volatile("s_waitcnt vmcnt(8)" ::: "memory");
  __builtin_amdgcn_s_barrier();
#pragma unroll
  for (int m = 0; m < 8; ++m)
    ra[0][m] = *reinterpret_cast<const s16x8*>(&S[0][aB + m * 512]);
#pragma unroll
  for (int n = 0; n < 4; ++n)
    rb[0][n] = *reinterpret_cast<const s16x8*>(&S[0][bB + n * 512]);
  int knext = 96;

#define PHASE(SLOT, CUR, NXT)                                                \
  {                                                                          \
    asm volatile("s_waitcnt vmcnt(4)" ::: "memory");                         \
    __builtin_amdgcn_s_barrier();                                            \
    const int kk = knext <= Km32 ? knext : Km32;                             \
    short* D = &S[(SLOT + 3) & 3][0];                                        \
    gload16(Ag0 + kk, D + dA);                                               \
    gload16(Ag1 + kk, D + dA + 512);                                         \
    gload16(Bg0 + kk, D + dB);                                               \
    gload16(Bg1 + kk, D + dB + 512);                                         \
    knext += 32;                                                             \
    const short* Sl = &S[(SLOT + 1) & 3][0];                                 \
    _Pragma("unroll")                                                        \
    for (int m = 0; m < 8; ++m)                                              \
      ra[NXT][m] = *reinterpret_cast<const s16x8*>(&Sl[aB + m * 512]);       \
    _Pragma("unroll")                                                        \
    for (int n = 0; n < 4; ++n)                                              \
      rb[NXT][n] = *reinterpret_cast<const s16x8*>(&Sl[bB + n * 512]);       \
    __builtin_amdgcn_sched_barrier(0);                                       \
    __builtin_amdgcn_s_setprio(1);                                           \
    _Pragma("unroll")                                                        \
    for (int m = 0; m < 8; ++m)                                              \
      _Pragma("unroll")                                                      \
      for (int n = 0; n < 4; ++n)                                            \
        acc[m][n] = MM(ra[CUR][m], rb[CUR][n], acc[m][n]);                   \
    __builtin_amdgcn_s_setprio(0);                                           \
  }

  const int NPH = K >> 5;                // K multiple of 128 -> NPH % 4 == 0
  for (int p = 0; p < NPH; p += 4) {
    PHASE(0, 0, 1) PHASE(1, 1, 0) PHASE(2, 0, 1) PHASE(3, 1, 0)
  }
#undef PHASE
  asm volatile("s_waitcnt vmcnt(0)" ::: "memory");

  const int row0 = brow + wm * 128 + fg * 4;
  const int col0 = bcol + wn * 64 + fr;

  if constexpr (EPI == 0) {
    short* Cb = reinterpret_cast<short*>(Cv);
    if (bcol < 1024) {                    // y columns -> fp16 [8192][1024]
#pragma unroll
      for (int m = 0; m < 8; ++m)
#pragma unroll
        for (int j = 0; j < 4; ++j) {
          const int row = row0 + m * 16 + j;
#pragma unroll
          for (int n = 0; n < 4; ++n)
            Cb[(size_t)row * ldc + col0 + n * 16] = f2hs(acc[m][n][j]);
        }
    } else {                              // v' columns -> bf16 into VT[b][o][t]
#pragma unroll
      for (int m = 0; m < 8; ++m)
#pragma unroll
        for (int j = 0; j < 4; ++j) {
          const int row = row0 + m * 16 + j;
          const int zb = row >> 11, s = row & 2047;
#pragma unroll
          for (int n = 0; n < 4; ++n) {
            const int d = col0 + n * 16 - 1024;
            Cv2[((size_t)(zb << 10) + d) * 2048 + s] = f2bs(acc[m][n][j]);
          }
        }
    }
  } else {
    // P = exp(dots) bf16; per-wave 64-col rowsum partial (shfl over fr
    // group), single non-atomic store per (row, bx, wn) -> auxw[z][row][32].
    short* Cb = reinterpret_cast<short*>(Cv) + (size_t)z * bsC;
    float* rp = auxw + (size_t)z * 2048 * 32;
#pragma unroll
    for (int m = 0; m < 8; ++m)
#pragma unroll
      for (int j = 0; j < 4; ++j) {
        const int row = row0 + m * 16 + j;
        float e[4];
#pragma unroll
        for (int n = 0; n < 4; ++n) {
          e[n] = exp2f(acc[m][n][j] * 1.4426950408889634f);
          Cb[(size_t)row * ldc + col0 + n * 16] = f2bs(e[n]);
        }
        float ps = (e[0] + e[1]) + (e[2] + e[3]);
        ps += __shfl_xor(ps, 1);
        ps += __shfl_xor(ps, 2);
        ps += __shfl_xor(ps, 4);
        ps += __shfl_xor(ps, 8);
        if (fr == 0) rp[(size_t)row * 32 + bx * 4 + wn] = ps;
      }
  }
}

// ---------------- 128x128 R1-core GEMM (out; rowsum from partials) ----------
__global__ __launch_bounds__(256, 2)
void gemm_out(const short* __restrict__ A, int lda, long long bsA,
              const short* __restrict__ B, int ldb, long long bsB,
              float* __restrict__ Cv, int ldc, long long bsC,
              int K, const float* __restrict__ aux, const float* __restrict__ auxw) {
  __shared__ __align__(16) short As[128 * 72];
  __shared__ __align__(16) short Bs[128 * 72];
  __shared__ float rcpLds[128];

  const int t = threadIdx.x;
  int bx, by, z;
  xcd_map<8, 16>(bx, by, z);
  A += (size_t)z * bsA;
  B += (size_t)z * bsB;

  const int brow = by * 128;
  const int bcol = bx * 128;

  const int srow = t >> 1;
  const int scol = (t & 1) << 5;
  const short* Ag = A + (size_t)(brow + srow) * lda + scol;
  const short* Bg = B + (size_t)(bcol + srow) * ldb + scol;
  short* Asw = &As[srow * 72 + scol];
  short* Bsw = &Bs[srow * 72 + scol];

  const int lane = t & 63;
  const int wid  = t >> 6;
  const int wr = (wid >> 1) * 64;
  const int wc = (wid & 1) * 64;
  const int fr = lane & 15;
  const int fg = lane >> 4;

  fx4 acc[4][4] = {};

  for (int kt = 0; kt < K; kt += 64) {
    s16x8 ar[4], br[4];
#pragma unroll
    for (int c = 0; c < 4; ++c) ar[c] = *reinterpret_cast<const s16x8*>(Ag + kt + c * 8);
#pragma unroll
    for (int c = 0; c < 4; ++c) br[c] = *reinterpret_cast<const s16x8*>(Bg + kt + c * 8);
    __syncthreads();
#pragma unroll
    for (int c = 0; c < 4; ++c) *reinterpret_cast<s16x8*>(Asw + c * 8) = ar[c];
#pragma unroll
    for (int c = 0; c < 4; ++c) *reinterpret_cast<s16x8*>(Bsw + c * 8) = br[c];
    __syncthreads();

#pragma unroll
    for (int kk = 0; kk < 64; kk += 32) {
      s16x8 af[4], bfv[4];
#pragma unroll
      for (int m = 0; m < 4; ++m)
        af[m] = *reinterpret_cast<const s16x8*>(&As[(wr + m * 16 + fr) * 72 + kk + fg * 8]);
#pragma unroll
      for (int n = 0; n < 4; ++n)
        bfv[n] = *reinterpret_cast<const s16x8*>(&Bs[(wc + n * 16 + fr) * 72 + kk + fg * 8]);
#pragma unroll
      for (int m = 0; m < 4; ++m)
#pragma unroll
        for (int n = 0; n < 4; ++n)
          acc[m][n] = __builtin_amdgcn_mfma_f32_16x16x32_bf16(af[m], bfv[n], acc[m][n], 0, 0, 0);
    }
  }

  // reduce the 32 rowsum partials per row into rcpLds (LDS is free now)
  __syncthreads();
  if (t < 128) {
    const float4* rp = reinterpret_cast<const float4*>(
        auxw + ((size_t)z * 2048 + brow + t) * 32);
    float s = 0.f;
#pragma unroll
    for (int i = 0; i < 8; ++i) {
      float4 v = rp[i];
      s += (v.x + v.y) + (v.z + v.w);
    }
    rcpLds[t] = 1.0f / s;
  }
  __syncthreads();

  // D layout: row = fg*4 + j, col = fr.
  const int row0 = brow + wr + fg * 4;
  const int col0 = bcol + wc + fr;
#pragma unroll
  for (int m = 0; m < 4; ++m)
#pragma unroll
    for (int j = 0; j < 4; ++j) {
      const int row = row0 + m * 16 + j;
      const float rcp = rcpLds[wr + m * 16 + fg * 4 + j];
#pragma unroll
      for (int n = 0; n < 4; ++n) {
        const int col = col0 + n * 16;
        Cv[(size_t)z * bsC + (size_t)row * ldc + col] = acc[m][n][j] * rcp + aux[col];
      }
    }
}

// ---------------- launch ----------------

extern "C" void kernel_launch(void* const* d_in, const int* in_sizes, int n_in,
                              void* d_out, int out_size, void* d_ws, size_t ws_size,
                              hipStream_t stream) {
  const float* x    = (const float*)d_in[0];   // [4,2048,1024]
  const float* Wqkv = (const float*)d_in[1];   // [1024,3072]
  const float* Wout = (const float*)d_in[2];   // [1024,1024]
  const float* bout = (const float*)d_in[3];   // [1024]
  float* out = (float*)d_out;                  // [4,2048,1024] fp32

  // workspace layout (bytes)
  char* ws = (char*)d_ws;
  short* xh    = (short*)(ws + 0);             //  16777216  fp16 x [8192][1024]
  short* WoutT = (short*)(ws + 16777216);      //   2097152  fp16 W_out^T [1024][1024]
  short* Wyv   = (short*)(ws + 18874368);      //   4194304  fp16 [M^T; Wvo^T] [2048][1024]
  short* y     = (short*)(ws + 23068672);      //  16777216  fp16 [8192][1024]
  short* VT    = (short*)(ws + 39845888);      //  16777216  bf16 v' [4][1024][2048]
  short* P     = (short*)(ws + 56623104);      //  33554432  bf16 [4][2048][2048]
  float* rsum_p= (float*)(ws + 90177536);      //   1048576  [4][2048][32] partials
  if (ws_size < 91226112) return;              // insufficient scratch -> visible failure

  cvt_f32_f16<<<8192, 256, 0, stream>>>(x, xh, 8388608 / 4);
  transpose_w<<<dim3(32, 32), 256, 0, stream>>>(Wout, 1024, 1024, WoutT);
  // M^T (scale folded) and Wvo^T -> Wyv (reads Wqkv f32 directly)
  prep_gemm64<<<dim3(16, 32), 256, 0, stream>>>(Wqkv, WoutT, Wyv);

  // yv = xh @ Wyv^T  (y cols 0-1023 -> y; v' -> VT)           256 blocks (1/CU)
  gemm256<0, 0, 8, 32><<<dim3(8, 32, 1), 512, 0, stream>>>(
      xh, 1024, 0, Wyv, 1024, 0, y, 1024, 0, 1024, VT, nullptr);
  // P = exp(y @ xh^T) + non-atomic rowsum partials             256 blocks (1/CU)
  gemm256<1, 0, 8, 8><<<dim3(8, 8, 4), 512, 0, stream>>>(
      y, 1024, 2048LL * 1024, xh, 1024, 2048LL * 1024,
      P, 2048, 2048LL * 2048, 1024, nullptr, rsum_p);
  // out = (P @ VT^T)/rowsum + bias  (rowsum from partials)     512 blocks (2/CU)
  gemm_out<<<dim3(8, 16, 4), 256, 0, stream>>>(
      P, 2048, 2048LL * 2048, VT, 2048, 1024LL * 2048,
      out, 1024, 2048LL * 1024, 2048, bout, rsum_p);
}

// Round 18
// 164.050 us; speedup vs baseline: 1.0032x; 1.0032x over previous
//
#include <hip/hip_runtime.h>
#include <hip/hip_bf16.h>

// ---------------------------------------------------------------------------
// Attention_58248346469030:  out = softmax((x@Wq)(x@Wk)^T * sc) @ (x@Wv) @ Wout + b
// B=4, S=2048, DIM=1024, INNER=1024 (full-dim attention, no head split).
//
// FINAL COMPOSITION (best measured, = R13/R16, 163.6us):
//   ALGEBRAIC FOLD: dots = x@(sc*Wq@Wk^T)@x^T, out = (P@(x@(Wv@Wout)))/l + b
//   prep:  xh = fp16(x); WoutT = W_out^T fp16; prep_gemm64 (reads Wqkv f32
//          directly) -> Wyv [2048][1024] fp16
//   1) yv  = xh @ Wyv^T : y fp16 [8192][1024], v' bf16 -> VT[b][o][t]
//   2) P   = exp(y @ xh^T)  bf16  (pure store epilogue)
//   3) out = (P @ VT^T)/rowsum + bias; rowsum via ones-MFMA on A=P fragments
//      (measured best of four variants: ones-MFMA 163.6 < partials 164.6 <
//       VALU 169.2 < atomics 173.9)
//   T1 bijective XCD swizzle on all big GEMMs (FETCH 139->33MB).
//
// Session ledger: algebraic fold -34us; XCD swizzle -6us; fusions -16us;
// five core-schedule restructures all null (cores pinned at 640-775 TF).
// ---------------------------------------------------------------------------

typedef short    s16x8 __attribute__((ext_vector_type(8)));
typedef short    s16x4 __attribute__((ext_vector_type(4)));
typedef float    fx4   __attribute__((ext_vector_type(4)));
typedef _Float16 h16x8 __attribute__((ext_vector_type(8)));

__device__ __forceinline__ short f2bs(float f) {            // f32 -> bf16 bits (RNE)
  __hip_bfloat16 h = __float2bfloat16(f);
  short s; __builtin_memcpy(&s, &h, 2); return s;
}
__device__ __forceinline__ short f2hs(float f) {            // f32 -> fp16 bits (RNE)
  _Float16 h = (_Float16)f;
  short s; __builtin_memcpy(&s, &h, 2); return s;
}

__device__ __forceinline__ void gload16(const void* g, void* l) {
  __builtin_amdgcn_global_load_lds(
      (const __attribute__((address_space(1))) void*)g,
      (__attribute__((address_space(3))) void*)l, 16, 0, 0);
}

// T1: bijective XCD-chunked swizzle (grids all %8==0).
template<int GX, int GY>
__device__ __forceinline__ void xcd_map(int& bx, int& by, int& bz) {
  const int glin = ((int)blockIdx.z * GY + (int)blockIdx.y) * GX + (int)blockIdx.x;
  const int nwg  = GX * GY * (int)gridDim.z;
  const int s    = (glin & 7) * (nwg >> 3) + (glin >> 3);
  bx = s % GX;
  const int t = s / GX;
  by = t % GY;
  bz = t / GY;
}

// ---------------- prep kernels ----------------

__global__ void cvt_f32_f16(const float* __restrict__ in, short* __restrict__ out, int n4) {
  int i = blockIdx.x * blockDim.x + threadIdx.x;
  if (i < n4) {
    float4 v = reinterpret_cast<const float4*>(in)[i];
    s16x4 o;
    o.x = f2hs(v.x); o.y = f2hs(v.y); o.z = f2hs(v.z); o.w = f2hs(v.w);
    reinterpret_cast<s16x4*>(out)[i] = o;
  }
}

// WT[n][k] = W[k][n], fp16 out.
__global__ void transpose_w(const float* __restrict__ W, int K, int N,
                            short* __restrict__ WT) {
  __shared__ float tile[32][33];
  int k0 = blockIdx.y * 32, n0 = blockIdx.x * 32;
  int r = threadIdx.x >> 5, c = threadIdx.x & 31;
  for (int rr = r; rr < 32; rr += 8)
    tile[rr][c] = W[(size_t)(k0 + rr) * N + n0 + c];
  __syncthreads();
  for (int rr = r; rr < 32; rr += 8)
    WT[(size_t)(n0 + rr) * K + k0 + c] = f2hs(tile[c][rr]);
}

// Weight-fold GEMMs, 64x64 tiles, K=1024, fp16 MFMA. Reads Wqkv in f32
// (converted in-register during staging); A for the Wvo fold is WoutT fp16.
// by<16 : M^T[e'][e]  = 0.125 * sum_d Wk[e'][d] Wq[e][d]    -> Wyv rows 0-1023
// by>=16: Wvo^T[o][e] =         sum_i WoutT[o][i] Wv[e][i]  -> Wyv rows 1024-2047
__global__ __launch_bounds__(256, 4)
void prep_gemm64(const float* __restrict__ Wqkv, const short* __restrict__ WoutT,
                 short* __restrict__ Wyv) {
  __shared__ __align__(16) short As[64 * 72];
  __shared__ __align__(16) short Bs[64 * 72];

  const bool isM = blockIdx.y < 16;
  const int arow0 = (blockIdx.y & 15) * 64;
  const int crow0 = arow0 + (isM ? 0 : 1024);
  const int bcol = blockIdx.x * 64;
  const float scale = isM ? 0.125f : 1.0f;

  const int t = threadIdx.x;
  const int r = t >> 2;
  const int sc = (t & 3) * 16;
  // A: isM -> Wqkv[arow0+r][1024 + sc + kt] (Wk, f32); else WoutT fp16
  const float* Agf = Wqkv + (size_t)(arow0 + r) * 3072 + 1024 + sc;
  const short* Agh = WoutT + (size_t)(arow0 + r) * 1024 + sc;
  // B: Wqkv[bcol+r][(isM?0:2048) + sc + kt] (Wq | Wv, f32)
  const float* Bgf = Wqkv + (size_t)(bcol + r) * 3072 + (isM ? 0 : 2048) + sc;

  short* Asw = &As[r * 72 + sc];
  short* Bsw = &Bs[r * 72 + sc];

  const int lane = t & 63;
  const int wid  = t >> 6;
  const int wm = wid >> 1, wn = wid & 1;
  const int fr = lane & 15, fg = lane >> 4;

  fx4 acc[2][2] = {};

  for (int kt = 0; kt < 1024; kt += 64) {
    s16x8 ar[2], br[2];
    if (isM) {
#pragma unroll
      for (int c = 0; c < 2; ++c) {
        float4 v0 = *reinterpret_cast<const float4*>(Agf + kt + c * 8);
        float4 v1 = *reinterpret_cast<const float4*>(Agf + kt + c * 8 + 4);
        ar[c][0] = f2hs(v0.x); ar[c][1] = f2hs(v0.y); ar[c][2] = f2hs(v0.z); ar[c][3] = f2hs(v0.w);
        ar[c][4] = f2hs(v1.x); ar[c][5] = f2hs(v1.y); ar[c][6] = f2hs(v1.z); ar[c][7] = f2hs(v1.w);
      }
    } else {
#pragma unroll
      for (int c = 0; c < 2; ++c)
        ar[c] = *reinterpret_cast<const s16x8*>(Agh + kt + c * 8);
    }
#pragma unroll
    for (int c = 0; c < 2; ++c) {
      float4 v0 = *reinterpret_cast<const float4*>(Bgf + kt + c * 8);
      float4 v1 = *reinterpret_cast<const float4*>(Bgf + kt + c * 8 + 4);
      br[c][0] = f2hs(v0.x); br[c][1] = f2hs(v0.y); br[c][2] = f2hs(v0.z); br[c][3] = f2hs(v0.w);
      br[c][4] = f2hs(v1.x); br[c][5] = f2hs(v1.y); br[c][6] = f2hs(v1.z); br[c][7] = f2hs(v1.w);
    }
    __syncthreads();
#pragma unroll
    for (int c = 0; c < 2; ++c) {
      *reinterpret_cast<s16x8*>(Asw + c * 8) = ar[c];
      *reinterpret_cast<s16x8*>(Bsw + c * 8) = br[c];
    }
    __syncthreads();
#pragma unroll
    for (int kk = 0; kk < 64; kk += 32) {
      s16x8 af[2], bf[2];
#pragma unroll
      for (int m = 0; m < 2; ++m)
        af[m] = *reinterpret_cast<const s16x8*>(&As[(wm * 32 + m * 16 + fr) * 72 + kk + fg * 8]);
#pragma unroll
      for (int n = 0; n < 2; ++n)
        bf[n] = *reinterpret_cast<const s16x8*>(&Bs[(wn * 32 + n * 16 + fr) * 72 + kk + fg * 8]);
#pragma unroll
      for (int m = 0; m < 2; ++m)
#pragma unroll
        for (int n = 0; n < 2; ++n)
          acc[m][n] = __builtin_amdgcn_mfma_f32_16x16x32_f16(
              __builtin_bit_cast(h16x8, af[m]), __builtin_bit_cast(h16x8, bf[n]),
              acc[m][n], 0, 0, 0);
    }
  }

  const int row0 = crow0 + wm * 32 + fg * 4;
  const int col0 = bcol + wn * 32 + fr;
#pragma unroll
  for (int m = 0; m < 2; ++m)
#pragma unroll
    for (int j = 0; j < 4; ++j) {
      const int row = row0 + m * 16 + j;
#pragma unroll
      for (int n = 0; n < 2; ++n)
        Wyv[(size_t)row * 1024 + col0 + n * 16] = f2hs(acc[m][n][j] * scale);
    }
}

// ---------------- 256x256 8-wave 4-slot ping-pong GEMM (R8 core + T1) ----------------
// C[M][N] = A[M][K] @ B'[N][K]^T
// EPI: 0 = yv write (cols <1024: y fp16; >=1024: v' bf16 -> VT=Cv2)
//      1 = exp -> bf16 (pure store)
template<int EPI, int DT, int GX, int GY>
__global__ __launch_bounds__(512, 2)
void gemm256(const short* __restrict__ A, int lda, long long bsA,
             const short* __restrict__ B, int ldb, long long bsB,
             void* __restrict__ Cv, int ldc, long long bsC,
             int K, short* __restrict__ Cv2) {
  __shared__ __align__(16) short S[4][16384];

  const int t = threadIdx.x;
  int bx, by, z;
  xcd_map<GX, GY>(bx, by, z);
  A += (size_t)z * bsA;
  B += (size_t)z * bsB;

  const int brow = by * 256;
  const int bcol = bx * 256;

  const int lane = t & 63;
  const int wid  = t >> 6;
  const int wm = wid >> 2;
  const int wn = wid & 3;
  const int fr = lane & 15;
  const int fg = lane >> 4;

  const int l2 = lane >> 2;
  const int gsrc = ((lane & 3) ^ ((lane >> 3) & 3)) * 8;
  const short* Ag0 = A + (size_t)(brow + wid * 32 + l2) * lda + gsrc;
  const short* Ag1 = Ag0 + (size_t)16 * lda;
  const short* Bg0 = B + (size_t)(bcol + wid * 32 + l2) * ldb + gsrc;
  const short* Bg1 = Bg0 + (size_t)16 * ldb;
  const int dA = wid * 1024;
  const int dB = 8192 + wid * 1024;

  const int gq = (fg ^ ((fr >> 1) & 3)) * 8;
  const int aB = (wm * 128 + fr) * 32 + gq;
  const int bB = 8192 + (wn * 64 + fr) * 32 + gq;

  fx4 acc[8][4] = {};
  s16x8 ra[2][8], rb[2][4];
  const int Km32 = K - 32;

  auto MM = [&](s16x8 av, s16x8 bv, fx4 c) -> fx4 {
    if constexpr (DT == 0)
      return __builtin_amdgcn_mfma_f32_16x16x32_f16(
          __builtin_bit_cast(h16x8, av), __builtin_bit_cast(h16x8, bv), c, 0, 0, 0);
    else
      return __builtin_amdgcn_mfma_f32_16x16x32_bf16(av, bv, c, 0, 0, 0);
  };

#pragma unroll
  for (int s = 0; s < 3; ++s) {
    const int kk = s * 32;
    gload16(Ag0 + kk, &S[s][dA]);
    gload16(Ag1 + kk, &S[s][dA + 512]);
    gload16(Bg0 + kk, &S[s][dB]);
    gload16(Bg1 + kk, &S[s][dB + 512]);
  }
  asm volatile("s_waitcnt vmcnt(8)" ::: "memory");
  __builtin_amdgcn_s_barrier();
#pragma unroll
  for (int m = 0; m < 8; ++m)
    ra[0][m] = *reinterpret_cast<const s16x8*>(&S[0][aB + m * 512]);
#pragma unroll
  for (int n = 0; n < 4; ++n)
    rb[0][n] = *reinterpret_cast<const s16x8*>(&S[0][bB + n * 512]);
  int knext = 96;

#define PHASE(SLOT, CUR, NXT)                                                \
  {                                                                          \
    asm volatile("s_waitcnt vmcnt(4)" ::: "memory");                         \
    __builtin_amdgcn_s_barrier();                                            \
    const int kk = knext <= Km32 ? knext : Km32;                             \
    short* D = &S[(SLOT + 3) & 3][0];                                        \
    gload16(Ag0 + kk, D + dA);                                               \
    gload16(Ag1 + kk, D + dA + 512);                                         \
    gload16(Bg0 + kk, D + dB);                                               \
    gload16(Bg1 + kk, D + dB + 512);                                         \
    knext += 32;                                                             \
    const short* Sl = &S[(SLOT + 1) & 3][0];                                 \
    _Pragma("unroll")                                                        \
    for (int m = 0; m < 8; ++m)                                              \
      ra[NXT][m] = *reinterpret_cast<const s16x8*>(&Sl[aB + m * 512]);       \
    _Pragma("unroll")                                                        \
    for (int n = 0; n < 4; ++n)                                              \
      rb[NXT][n] = *reinterpret_cast<const s16x8*>(&Sl[bB + n * 512]);       \
    __builtin_amdgcn_sched_barrier(0);                                       \
    __builtin_amdgcn_s_setprio(1);                                           \
    _Pragma("unroll")                                                        \
    for (int m = 0; m < 8; ++m)                                              \
      _Pragma("unroll")                                                      \
      for (int n = 0; n < 4; ++n)                                            \
        acc[m][n] = MM(ra[CUR][m], rb[CUR][n], acc[m][n]);                   \
    __builtin_amdgcn_s_setprio(0);                                           \
  }

  const int NPH = K >> 5;                // K multiple of 128 -> NPH % 4 == 0
  for (int p = 0; p < NPH; p += 4) {
    PHASE(0, 0, 1) PHASE(1, 1, 0) PHASE(2, 0, 1) PHASE(3, 1, 0)
  }
#undef PHASE
  asm volatile("s_waitcnt vmcnt(0)" ::: "memory");

  const int row0 = brow + wm * 128 + fg * 4;
  const int col0 = bcol + wn * 64 + fr;

  if constexpr (EPI == 0) {
    short* Cb = reinterpret_cast<short*>(Cv);
    if (bcol < 1024) {                    // y columns -> fp16 [8192][1024]
#pragma unroll
      for (int m = 0; m < 8; ++m)
#pragma unroll
        for (int j = 0; j < 4; ++j) {
          const int row = row0 + m * 16 + j;
#pragma unroll
          for (int n = 0; n < 4; ++n)
            Cb[(size_t)row * ldc + col0 + n * 16] = f2hs(acc[m][n][j]);
        }
    } else {                              // v' columns -> bf16 into VT[b][o][t]
#pragma unroll
      for (int m = 0; m < 8; ++m)
#pragma unroll
        for (int j = 0; j < 4; ++j) {
          const int row = row0 + m * 16 + j;
          const int zb = row >> 11, s = row & 2047;
#pragma unroll
          for (int n = 0; n < 4; ++n) {
            const int d = col0 + n * 16 - 1024;
            Cv2[((size_t)(zb << 10) + d) * 2048 + s] = f2bs(acc[m][n][j]);
          }
        }
    }
  } else {
    // P = exp(dots) bf16, pure store (rowsum computed in gemm_out)
    short* Cb = reinterpret_cast<short*>(Cv) + (size_t)z * bsC;
#pragma unroll
    for (int m = 0; m < 8; ++m)
#pragma unroll
      for (int j = 0; j < 4; ++j) {
        const int row = row0 + m * 16 + j;
#pragma unroll
        for (int n = 0; n < 4; ++n)
          Cb[(size_t)row * ldc + col0 + n * 16] =
              f2bs(exp2f(acc[m][n][j] * 1.4426950408889634f));
      }
  }
}

// ---------------- 128x128 R1-core GEMM (out; fused rowsum via ones-MFMA) ----
__global__ __launch_bounds__(256, 2)
void gemm_out(const short* __restrict__ A, int lda, long long bsA,
              const short* __restrict__ B, int ldb, long long bsB,
              float* __restrict__ Cv, int ldc, long long bsC,
              int K, const float* __restrict__ aux) {
  __shared__ __align__(16) short As[128 * 72];
  __shared__ __align__(16) short Bs[128 * 72];

  const int t = threadIdx.x;
  int bx, by, z;
  xcd_map<8, 16>(bx, by, z);
  A += (size_t)z * bsA;
  B += (size_t)z * bsB;

  const int brow = by * 128;
  const int bcol = bx * 128;

  const int srow = t >> 1;
  const int scol = (t & 1) << 5;
  const short* Ag = A + (size_t)(brow + srow) * lda + scol;
  const short* Bg = B + (size_t)(bcol + srow) * ldb + scol;
  short* Asw = &As[srow * 72 + scol];
  short* Bsw = &Bs[srow * 72 + scol];

  const int lane = t & 63;
  const int wid  = t >> 6;
  const int wr = (wid >> 1) * 64;
  const int wc = (wid & 1) * 64;
  const int fr = lane & 15;
  const int fg = lane >> 4;

  fx4 acc[4][4] = {};
  fx4 acc_rs[4] = {};                    // rowsum accumulator (ones-MFMA)
  s16x8 ones;
#pragma unroll
  for (int i = 0; i < 8; ++i) ones[i] = (short)0x3F80;   // bf16 1.0

  for (int kt = 0; kt < K; kt += 64) {
    s16x8 ar[4], br[4];
#pragma unroll
    for (int c = 0; c < 4; ++c) ar[c] = *reinterpret_cast<const s16x8*>(Ag + kt + c * 8);
#pragma unroll
    for (int c = 0; c < 4; ++c) br[c] = *reinterpret_cast<const s16x8*>(Bg + kt + c * 8);
    __syncthreads();
#pragma unroll
    for (int c = 0; c < 4; ++c) *reinterpret_cast<s16x8*>(Asw + c * 8) = ar[c];
#pragma unroll
    for (int c = 0; c < 4; ++c) *reinterpret_cast<s16x8*>(Bsw + c * 8) = br[c];
    __syncthreads();

#pragma unroll
    for (int kk = 0; kk < 64; kk += 32) {
      s16x8 af[4], bfv[4];
#pragma unroll
      for (int m = 0; m < 4; ++m)
        af[m] = *reinterpret_cast<const s16x8*>(&As[(wr + m * 16 + fr) * 72 + kk + fg * 8]);
#pragma unroll
      for (int n = 0; n < 4; ++n)
        bfv[n] = *reinterpret_cast<const s16x8*>(&Bs[(wc + n * 16 + fr) * 72 + kk + fg * 8]);
#pragma unroll
      for (int m = 0; m < 4; ++m) {
#pragma unroll
        for (int n = 0; n < 4; ++n)
          acc[m][n] = __builtin_amdgcn_mfma_f32_16x16x32_bf16(af[m], bfv[n], acc[m][n], 0, 0, 0);
        acc_rs[m] = __builtin_amdgcn_mfma_f32_16x16x32_bf16(af[m], ones, acc_rs[m], 0, 0, 0);
      }
    }
  }

  // D layout: row = fg*4 + j, col = fr. acc_rs[m][j] = rowsum(row0 + m*16 + j)
  const int row0 = brow + wr + fg * 4;
  const int col0 = bcol + wc + fr;
#pragma unroll
  for (int m = 0; m < 4; ++m)
#pragma unroll
    for (int j = 0; j < 4; ++j) {
      const int row = row0 + m * 16 + j;
      const float rcp = 1.0f / acc_rs[m][j];
#pragma unroll
      for (int n = 0; n < 4; ++n) {
        const int col = col0 + n * 16;
        Cv[(size_t)z * bsC + (size_t)row * ldc + col] = acc[m][n][j] * rcp + aux[col];
      }
    }
}

// ---------------- launch ----------------

extern "C" void kernel_launch(void* const* d_in, const int* in_sizes, int n_in,
                              void* d_out, int out_size, void* d_ws, size_t ws_size,
                              hipStream_t stream) {
  const float* x    = (const float*)d_in[0];   // [4,2048,1024]
  const float* Wqkv = (const float*)d_in[1];   // [1024,3072]
  const float* Wout = (const float*)d_in[2];   // [1024,1024]
  const float* bout = (const float*)d_in[3];   // [1024]
  float* out = (float*)d_out;                  // [4,2048,1024] fp32

  // workspace layout (bytes)
  char* ws = (char*)d_ws;
  short* xh    = (short*)(ws + 0);             //  16777216  fp16 x [8192][1024]
  short* WoutT = (short*)(ws + 16777216);      //   2097152  fp16 W_out^T [1024][1024]
  short* Wyv   = (short*)(ws + 18874368);      //   4194304  fp16 [M^T; Wvo^T] [2048][1024]
  short* y     = (short*)(ws + 23068672);      //  16777216  fp16 [8192][1024]
  short* VT    = (short*)(ws + 39845888);      //  16777216  bf16 v' [4][1024][2048]
  short* P     = (short*)(ws + 56623104);      //  33554432  bf16 [4][2048][2048]
  if (ws_size < 90177536) return;              // insufficient scratch -> visible failure

  cvt_f32_f16<<<8192, 256, 0, stream>>>(x, xh, 8388608 / 4);
  transpose_w<<<dim3(32, 32), 256, 0, stream>>>(Wout, 1024, 1024, WoutT);
  // M^T (scale folded) and Wvo^T -> Wyv (reads Wqkv f32 directly)
  prep_gemm64<<<dim3(16, 32), 256, 0, stream>>>(Wqkv, WoutT, Wyv);

  // yv = xh @ Wyv^T  (y cols 0-1023 -> y; v' -> VT)           256 blocks (1/CU)
  gemm256<0, 0, 8, 32><<<dim3(8, 32, 1), 512, 0, stream>>>(
      xh, 1024, 0, Wyv, 1024, 0, y, 1024, 0, 1024, VT);
  // P = exp(y @ xh^T)                                          256 blocks (1/CU)
  gemm256<1, 0, 8, 8><<<dim3(8, 8, 4), 512, 0, stream>>>(
      y, 1024, 2048LL * 1024, xh, 1024, 2048LL * 1024,
      P, 2048, 2048LL * 2048, 1024, nullptr);
  // out = (P @ VT^T)/rowsum + bias  (rowsum fused via ones-MFMA)  512 blocks
  gemm_out<<<dim3(8, 16, 4), 256, 0, stream>>>(
      P, 2048, 2048LL * 2048, VT, 2048, 1024LL * 2048,
      out, 1024, 2048LL * 1024, 2048, bout);
}

// Round 19
// 162.248 us; speedup vs baseline: 1.0144x; 1.0111x over previous
//
#include <hip/hip_runtime.h>
#include <hip/hip_bf16.h>

// ---------------------------------------------------------------------------
// Attention_58248346469030:  out = softmax((x@Wq)(x@Wk)^T * sc) @ (x@Wv) @ Wout + b
// B=4, S=2048, DIM=1024, INNER=1024 (full-dim attention, no head split).
//
// ALGEBRAIC FOLD (R10): dots = x@(sc*Wq@Wk^T)@x^T, out = (P@(x@(Wv@Wout)))/l + b
//   prep:  xh = fp16(x); WoutT; prep_gemm64 -> Wyv [2048][1024] fp16
//   1) yv  = xh @ Wyv^T : y fp16, v' bf16 -> VT      (8-PHASE CORE, this round)
//   2) P   = exp(y @ xh^T) bf16                      (8-PHASE CORE, this round)
//   3) out = (P @ VT^T)/rowsum + bias (rowsum ones-MFMA; R16 measured-best)
//
// NEW CORE (faithful m201 8-phase port): 256x256, BK=64, 8 waves (2Mx4N),
// dbuf LDS 128KB. Phase = {ds-read 1 quadrant (4-12 b128) || stage 1 half-tile
// (2 gload_lds) -> barrier -> lgkmcnt(0) -> setprio(1) 16 MFMA setprio(0) ->
// barrier}; vmcnt(6) ONLY at phases 4/8 (3 half-tiles in flight). Halves are
// quadrant-aligned row stripes so every stage dest was last read >=1 phase
// earlier (race-freedom traced for prologue/steady/tail). T2 swizzle
// granule ^= (row&7) on stage source + ds_read (verified recipe, Guideline 4).
// ---------------------------------------------------------------------------

typedef short    s16x8 __attribute__((ext_vector_type(8)));
typedef short    s16x4 __attribute__((ext_vector_type(4)));
typedef float    fx4   __attribute__((ext_vector_type(4)));
typedef _Float16 h16x8 __attribute__((ext_vector_type(8)));

__device__ __forceinline__ short f2bs(float f) {            // f32 -> bf16 bits (RNE)
  __hip_bfloat16 h = __float2bfloat16(f);
  short s; __builtin_memcpy(&s, &h, 2); return s;
}
__device__ __forceinline__ short f2hs(float f) {            // f32 -> fp16 bits (RNE)
  _Float16 h = (_Float16)f;
  short s; __builtin_memcpy(&s, &h, 2); return s;
}

__device__ __forceinline__ void gload16(const void* g, void* l) {
  __builtin_amdgcn_global_load_lds(
      (const __attribute__((address_space(1))) void*)g,
      (__attribute__((address_space(3))) void*)l, 16, 0, 0);
}

// T1: bijective XCD-chunked swizzle (grids all %8==0).
template<int GX, int GY>
__device__ __forceinline__ void xcd_map(int& bx, int& by, int& bz) {
  const int glin = ((int)blockIdx.z * GY + (int)blockIdx.y) * GX + (int)blockIdx.x;
  const int nwg  = GX * GY * (int)gridDim.z;
  const int s    = (glin & 7) * (nwg >> 3) + (glin >> 3);
  bx = s % GX;
  const int t = s / GX;
  by = t % GY;
  bz = t / GY;
}

// ---------------- prep kernels ----------------

__global__ void cvt_f32_f16(const float* __restrict__ in, short* __restrict__ out, int n4) {
  int i = blockIdx.x * blockDim.x + threadIdx.x;
  if (i < n4) {
    float4 v = reinterpret_cast<const float4*>(in)[i];
    s16x4 o;
    o.x = f2hs(v.x); o.y = f2hs(v.y); o.z = f2hs(v.z); o.w = f2hs(v.w);
    reinterpret_cast<s16x4*>(out)[i] = o;
  }
}

__global__ void transpose_w(const float* __restrict__ W, int K, int N,
                            short* __restrict__ WT) {
  __shared__ float tile[32][33];
  int k0 = blockIdx.y * 32, n0 = blockIdx.x * 32;
  int r = threadIdx.x >> 5, c = threadIdx.x & 31;
  for (int rr = r; rr < 32; rr += 8)
    tile[rr][c] = W[(size_t)(k0 + rr) * N + n0 + c];
  __syncthreads();
  for (int rr = r; rr < 32; rr += 8)
    WT[(size_t)(n0 + rr) * K + k0 + c] = f2hs(tile[c][rr]);
}

// Weight-fold GEMMs, 64x64 tiles, K=1024, fp16 MFMA (reads Wqkv f32 directly).
__global__ __launch_bounds__(256, 4)
void prep_gemm64(const float* __restrict__ Wqkv, const short* __restrict__ WoutT,
                 short* __restrict__ Wyv) {
  __shared__ __align__(16) short As[64 * 72];
  __shared__ __align__(16) short Bs[64 * 72];

  const bool isM = blockIdx.y < 16;
  const int arow0 = (blockIdx.y & 15) * 64;
  const int crow0 = arow0 + (isM ? 0 : 1024);
  const int bcol = blockIdx.x * 64;
  const float scale = isM ? 0.125f : 1.0f;

  const int t = threadIdx.x;
  const int r = t >> 2;
  const int sc = (t & 3) * 16;
  const float* Agf = Wqkv + (size_t)(arow0 + r) * 3072 + 1024 + sc;
  const short* Agh = WoutT + (size_t)(arow0 + r) * 1024 + sc;
  const float* Bgf = Wqkv + (size_t)(bcol + r) * 3072 + (isM ? 0 : 2048) + sc;

  short* Asw = &As[r * 72 + sc];
  short* Bsw = &Bs[r * 72 + sc];

  const int lane = t & 63;
  const int wid  = t >> 6;
  const int wm = wid >> 1, wn = wid & 1;
  const int fr = lane & 15, fg = lane >> 4;

  fx4 acc[2][2] = {};

  for (int kt = 0; kt < 1024; kt += 64) {
    s16x8 ar[2], br[2];
    if (isM) {
#pragma unroll
      for (int c = 0; c < 2; ++c) {
        float4 v0 = *reinterpret_cast<const float4*>(Agf + kt + c * 8);
        float4 v1 = *reinterpret_cast<const float4*>(Agf + kt + c * 8 + 4);
        ar[c][0] = f2hs(v0.x); ar[c][1] = f2hs(v0.y); ar[c][2] = f2hs(v0.z); ar[c][3] = f2hs(v0.w);
        ar[c][4] = f2hs(v1.x); ar[c][5] = f2hs(v1.y); ar[c][6] = f2hs(v1.z); ar[c][7] = f2hs(v1.w);
      }
    } else {
#pragma unroll
      for (int c = 0; c < 2; ++c)
        ar[c] = *reinterpret_cast<const s16x8*>(Agh + kt + c * 8);
    }
#pragma unroll
    for (int c = 0; c < 2; ++c) {
      float4 v0 = *reinterpret_cast<const float4*>(Bgf + kt + c * 8);
      float4 v1 = *reinterpret_cast<const float4*>(Bgf + kt + c * 8 + 4);
      br[c][0] = f2hs(v0.x); br[c][1] = f2hs(v0.y); br[c][2] = f2hs(v0.z); br[c][3] = f2hs(v0.w);
      br[c][4] = f2hs(v1.x); br[c][5] = f2hs(v1.y); br[c][6] = f2hs(v1.z); br[c][7] = f2hs(v1.w);
    }
    __syncthreads();
#pragma unroll
    for (int c = 0; c < 2; ++c) {
      *reinterpret_cast<s16x8*>(Asw + c * 8) = ar[c];
      *reinterpret_cast<s16x8*>(Bsw + c * 8) = br[c];
    }
    __syncthreads();
#pragma unroll
    for (int kk = 0; kk < 64; kk += 32) {
      s16x8 af[2], bf[2];
#pragma unroll
      for (int m = 0; m < 2; ++m)
        af[m] = *reinterpret_cast<const s16x8*>(&As[(wm * 32 + m * 16 + fr) * 72 + kk + fg * 8]);
#pragma unroll
      for (int n = 0; n < 2; ++n)
        bf[n] = *reinterpret_cast<const s16x8*>(&Bs[(wn * 32 + n * 16 + fr) * 72 + kk + fg * 8]);
#pragma unroll
      for (int m = 0; m < 2; ++m)
#pragma unroll
        for (int n = 0; n < 2; ++n)
          acc[m][n] = __builtin_amdgcn_mfma_f32_16x16x32_f16(
              __builtin_bit_cast(h16x8, af[m]), __builtin_bit_cast(h16x8, bf[n]),
              acc[m][n], 0, 0, 0);
    }
  }

  const int row0 = crow0 + wm * 32 + fg * 4;
  const int col0 = bcol + wn * 32 + fr;
#pragma unroll
  for (int m = 0; m < 2; ++m)
#pragma unroll
    for (int j = 0; j < 4; ++j) {
      const int row = row0 + m * 16 + j;
#pragma unroll
      for (int n = 0; n < 2; ++n)
        Wyv[(size_t)row * 1024 + col0 + n * 16] = f2hs(acc[m][n][j] * scale);
    }
}

// ---------------- 256x256 8-PHASE GEMM (m201 template port + T1/T2) --------
// C[M][N] = A[M][K] @ B'[N][K]^T, K multiple of 128 (NT even).
// EPI: 0 = yv write (cols <1024: y fp16; >=1024: v' bf16 -> VT=Cv2)
//      1 = exp -> bf16 (pure store)
template<int EPI, int DT, int GX, int GY>
__global__ __launch_bounds__(512, 2)
void gemm8p(const short* __restrict__ A, int lda, long long bsA,
            const short* __restrict__ B, int ldb, long long bsB,
            void* __restrict__ Cv, int ldc, long long bsC,
            int K, short* __restrict__ Cv2) {
  __shared__ __align__(16) short As[2][16384];   // 2 x 32KB (256 rows x 64 k)
  __shared__ __align__(16) short Bs[2][16384];   // 2 x 32KB

  const int t = threadIdx.x;
  int bx, by, z;
  xcd_map<GX, GY>(bx, by, z);
  A += (size_t)z * bsA;
  B += (size_t)z * bsB;

  const int brow = by * 256;
  const int bcol = bx * 256;

  const int lane = t & 63;
  const int wid  = t >> 6;
  const int wm = wid >> 2;               // 0/1
  const int wn = wid & 3;                // 0..3
  const int fr = lane & 15;
  const int fg = lane >> 4;
  const int f7 = fr & 7;
  const int g0 = fg ^ f7;                // swizzled granule, kk=0
  const int g1 = g0 ^ 4;                 // kk=32 (logical granule fg+4)

  // ---- staging geometry: half-tile = 16KB = 2 block-wide gload16 issues.
  // A-half h = rows {h*64..h*64+63, 128+h*64..} (quadrant-aligned stripes);
  // B-half h = rows {blk*64 + h*32 .. +31, blk=0..3}.
  // T2: LDS (row, granule g') holds global granule g' ^ (row&7); row&7=(t>>3)&7.
  const int r0 = t >> 3;                       // 0..63
  const int c8 = t & 7;
  const int swc = (c8 ^ (r0 & 7)) * 8;         // shorts
  const short* Ag = A + (size_t)(brow + r0) * lda + swc;
  const int rB0 = ((r0 >> 5) << 6) + (r0 & 31);
  const short* Bg = B + (size_t)(bcol + rB0) * ldb + swc;
  const int dstA = r0 * 64 + c8 * 8;           // shorts
  const int dstB = rB0 * 64 + c8 * 8;

#define STG_A(BUF, H, KT) {                                                  \
    const short* s_ = Ag + (size_t)(H) * 64 * lda + (KT);                    \
    gload16(s_,                     &As[BUF][(H) * 4096 + dstA]);            \
    gload16(s_ + (size_t)128 * lda, &As[BUF][8192 + (H) * 4096 + dstA]);     \
  }
#define STG_B(BUF, H, KT) {                                                  \
    const short* s_ = Bg + (size_t)(H) * 32 * ldb + (KT);                    \
    gload16(s_,                     &Bs[BUF][(H) * 2048 + dstB]);            \
    gload16(s_ + (size_t)128 * ldb, &Bs[BUF][8192 + (H) * 2048 + dstB]);     \
  }
#define BARRIER  __builtin_amdgcn_s_barrier()
#define LGKM0    { asm volatile("s_waitcnt lgkmcnt(0)" ::: "memory");        \
                   __builtin_amdgcn_sched_barrier(0); }
#define VM6      asm volatile("s_waitcnt vmcnt(6)" ::: "memory")

  fx4 acc[8][4] = {};
  s16x8 a[8][2], b[4][2];

  auto MM = [&](s16x8 av, s16x8 bv, fx4 c) -> fx4 {
    if constexpr (DT == 0)
      return __builtin_amdgcn_mfma_f32_16x16x32_f16(
          __builtin_bit_cast(h16x8, av), __builtin_bit_cast(h16x8, bv), c, 0, 0, 0);
    else
      return __builtin_amdgcn_mfma_f32_16x16x32_bf16(av, bv, c, 0, 0, 0);
  };

#define RDA4(P, M0)                                                          \
  _Pragma("unroll")                                                          \
  for (int mm = 0; mm < 4; ++mm) {                                           \
    const int ro = (wm * 128 + ((M0) + mm) * 16 + fr) * 64;                  \
    a[(M0) + mm][0] = *reinterpret_cast<const s16x8*>(&(P)[ro + g0 * 8]);    \
    a[(M0) + mm][1] = *reinterpret_cast<const s16x8*>(&(P)[ro + g1 * 8]);    \
  }
#define RDB2(P, N0)                                                          \
  _Pragma("unroll")                                                          \
  for (int nn = 0; nn < 2; ++nn) {                                           \
    const int ro = (wn * 64 + ((N0) + nn) * 16 + fr) * 64;                   \
    b[(N0) + nn][0] = *reinterpret_cast<const s16x8*>(&(P)[ro + g0 * 8]);    \
    b[(N0) + nn][1] = *reinterpret_cast<const s16x8*>(&(P)[ro + g1 * 8]);    \
  }
#define MMQUAD(M0, N0)                                                       \
  __builtin_amdgcn_s_setprio(1);                                             \
  _Pragma("unroll")                                                          \
  for (int mm = 0; mm < 4; ++mm)                                             \
    _Pragma("unroll")                                                        \
    for (int nn = 0; nn < 2; ++nn)                                           \
      _Pragma("unroll")                                                      \
      for (int kk = 0; kk < 2; ++kk)                                         \
        acc[(M0) + mm][(N0) + nn] =                                          \
            MM(a[(M0) + mm][kk], b[(N0) + nn][kk], acc[(M0) + mm][(N0) + nn]); \
  __builtin_amdgcn_s_setprio(0);

  const int NT = K >> 6;                 // 16 here (even)

  // ---- prologue: tile0 full + tile1 {A0,A1,B0}; drain tile0 (vmcnt(6)) ----
  STG_A(0, 0, 0) STG_A(0, 1, 0) STG_B(0, 0, 0) STG_B(0, 1, 0)
  STG_A(1, 0, 64) STG_A(1, 1, 64) STG_B(1, 0, 64)
  VM6;
  BARRIER;

  const short* A0p = &As[0][0]; const short* A1p = &As[1][0];
  const short* B0p = &Bs[0][0]; const short* B1p = &Bs[1][0];

  for (int it = 0; it < (NT >> 1); ++it) {
    const int T = it << 1;
    const int kt1 = (T + 1) << 6;
    const int kt2 = ((T + 2) < NT ? (T + 2) : NT - 1) << 6;
    const int kt3 = ((T + 3) < NT ? (T + 3) : NT - 1) << 6;

    // p1/Q1(tile T, buf0): reads A-half0 + B-half0; stage (T+1).B1 -> buf1
    RDA4(A0p, 0) RDB2(B0p, 0)
    STG_B(1, 1, kt1)
    BARRIER; LGKM0; MMQUAD(0, 0) BARRIER;
    // p2/Q2: reads A-half1; stage (T+2).A0 -> buf0 (A-half0 last read p1)
    RDA4(A0p, 4)
    STG_A(0, 0, kt2)
    BARRIER; LGKM0; MMQUAD(4, 0) BARRIER;
    // p3/Q3: reads B-half1; stage (T+2).A1 -> buf0 (A-half1 last read p2)
    RDB2(B0p, 2)
    STG_A(0, 1, kt2)
    BARRIER; LGKM0; MMQUAD(0, 2) BARRIER;
    // p4/Q4: no reads; stage (T+2).B0 -> buf0 (B-half0 last read p1); vmcnt(6)
    STG_B(0, 0, kt2)
    BARRIER; MMQUAD(4, 2) VM6; BARRIER;   // tile T+1 fully landed

    // p5/Q1(tile T+1, buf1); stage (T+2).B1 -> buf0 (B-half1 last read p3)
    RDA4(A1p, 0) RDB2(B1p, 0)
    STG_B(0, 1, kt2)
    BARRIER; LGKM0; MMQUAD(0, 0) BARRIER;
    // p6/Q2; stage (T+3).A0 -> buf1 (A-half0 last read p5)
    RDA4(A1p, 4)
    STG_A(1, 0, kt3)
    BARRIER; LGKM0; MMQUAD(4, 0) BARRIER;
    // p7/Q3; stage (T+3).A1 -> buf1 (A-half1 last read p6)
    RDB2(B1p, 2)
    STG_A(1, 1, kt3)
    BARRIER; LGKM0; MMQUAD(0, 2) BARRIER;
    // p8/Q4; stage (T+3).B0 -> buf1 (B-half0 last read p5); vmcnt(6)
    STG_B(1, 0, kt3)
    BARRIER; MMQUAD(4, 2) VM6; BARRIER;   // tile T+2 fully landed
  }
  asm volatile("s_waitcnt vmcnt(0)" ::: "memory");

#undef STG_A
#undef STG_B
#undef BARRIER
#undef LGKM0
#undef VM6
#undef RDA4
#undef RDB2
#undef MMQUAD

  // ---- epilogue: D row = fg*4 + j, col = fr (per 16x16 frag) ----
  const int row0 = brow + wm * 128 + fg * 4;
  const int col0 = bcol + wn * 64 + fr;

  if constexpr (EPI == 0) {
    short* Cb = reinterpret_cast<short*>(Cv);
    if (bcol < 1024) {                    // y columns -> fp16 [8192][1024]
#pragma unroll
      for (int m = 0; m < 8; ++m)
#pragma unroll
        for (int j = 0; j < 4; ++j) {
          const int row = row0 + m * 16 + j;
#pragma unroll
          for (int n = 0; n < 4; ++n)
            Cb[(size_t)row * ldc + col0 + n * 16] = f2hs(acc[m][n][j]);
        }
    } else {                              // v' columns -> bf16 into VT[b][o][t]
#pragma unroll
      for (int m = 0; m < 8; ++m)
#pragma unroll
        for (int j = 0; j < 4; ++j) {
          const int row = row0 + m * 16 + j;
          const int zb = row >> 11, s = row & 2047;
#pragma unroll
          for (int n = 0; n < 4; ++n) {
            const int d = col0 + n * 16 - 1024;
            Cv2[((size_t)(zb << 10) + d) * 2048 + s] = f2bs(acc[m][n][j]);
          }
        }
    }
  } else {
    // P = exp(dots) bf16, pure store (rowsum computed in gemm_out)
    short* Cb = reinterpret_cast<short*>(Cv) + (size_t)z * bsC;
#pragma unroll
    for (int m = 0; m < 8; ++m)
#pragma unroll
      for (int j = 0; j < 4; ++j) {
        const int row = row0 + m * 16 + j;
#pragma unroll
        for (int n = 0; n < 4; ++n)
          Cb[(size_t)row * ldc + col0 + n * 16] =
              f2bs(exp2f(acc[m][n][j] * 1.4426950408889634f));
      }
  }
}

// ---------------- 128x128 R1-core GEMM (out; fused rowsum via ones-MFMA) ----
__global__ __launch_bounds__(256, 2)
void gemm_out(const short* __restrict__ A, int lda, long long bsA,
              const short* __restrict__ B, int ldb, long long bsB,
              float* __restrict__ Cv, int ldc, long long bsC,
              int K, const float* __restrict__ aux) {
  __shared__ __align__(16) short As[128 * 72];
  __shared__ __align__(16) short Bs[128 * 72];

  const int t = threadIdx.x;
  int bx, by, z;
  xcd_map<8, 16>(bx, by, z);
  A += (size_t)z * bsA;
  B += (size_t)z * bsB;

  const int brow = by * 128;
  const int bcol = bx * 128;

  const int srow = t >> 1;
  const int scol = (t & 1) << 5;
  const short* Ag = A + (size_t)(brow + srow) * lda + scol;
  const short* Bg = B + (size_t)(bcol + srow) * ldb + scol;
  short* Asw = &As[srow * 72 + scol];
  short* Bsw = &Bs[srow * 72 + scol];

  const int lane = t & 63;
  const int wid  = t >> 6;
  const int wr = (wid >> 1) * 64;
  const int wc = (wid & 1) * 64;
  const int fr = lane & 15;
  const int fg = lane >> 4;

  fx4 acc[4][4] = {};
  fx4 acc_rs[4] = {};
  s16x8 ones;
#pragma unroll
  for (int i = 0; i < 8; ++i) ones[i] = (short)0x3F80;   // bf16 1.0

  for (int kt = 0; kt < K; kt += 64) {
    s16x8 ar[4], br[4];
#pragma unroll
    for (int c = 0; c < 4; ++c) ar[c] = *reinterpret_cast<const s16x8*>(Ag + kt + c * 8);
#pragma unroll
    for (int c = 0; c < 4; ++c) br[c] = *reinterpret_cast<const s16x8*>(Bg + kt + c * 8);
    __syncthreads();
#pragma unroll
    for (int c = 0; c < 4; ++c) *reinterpret_cast<s16x8*>(Asw + c * 8) = ar[c];
#pragma unroll
    for (int c = 0; c < 4; ++c) *reinterpret_cast<s16x8*>(Bsw + c * 8) = br[c];
    __syncthreads();

#pragma unroll
    for (int kk = 0; kk < 64; kk += 32) {
      s16x8 af[4], bfv[4];
#pragma unroll
      for (int m = 0; m < 4; ++m)
        af[m] = *reinterpret_cast<const s16x8*>(&As[(wr + m * 16 + fr) * 72 + kk + fg * 8]);
#pragma unroll
      for (int n = 0; n < 4; ++n)
        bfv[n] = *reinterpret_cast<const s16x8*>(&Bs[(wc + n * 16 + fr) * 72 + kk + fg * 8]);
#pragma unroll
      for (int m = 0; m < 4; ++m) {
#pragma unroll
        for (int n = 0; n < 4; ++n)
          acc[m][n] = __builtin_amdgcn_mfma_f32_16x16x32_bf16(af[m], bfv[n], acc[m][n], 0, 0, 0);
        acc_rs[m] = __builtin_amdgcn_mfma_f32_16x16x32_bf16(af[m], ones, acc_rs[m], 0, 0, 0);
      }
    }
  }

  const int row0 = brow + wr + fg * 4;
  const int col0 = bcol + wc + fr;
#pragma unroll
  for (int m = 0; m < 4; ++m)
#pragma unroll
    for (int j = 0; j < 4; ++j) {
      const int row = row0 + m * 16 + j;
      const float rcp = 1.0f / acc_rs[m][j];
#pragma unroll
      for (int n = 0; n < 4; ++n) {
        const int col = col0 + n * 16;
        Cv[(size_t)z * bsC + (size_t)row * ldc + col] = acc[m][n][j] * rcp + aux[col];
      }
    }
}

// ---------------- launch ----------------

extern "C" void kernel_launch(void* const* d_in, const int* in_sizes, int n_in,
                              void* d_out, int out_size, void* d_ws, size_t ws_size,
                              hipStream_t stream) {
  const float* x    = (const float*)d_in[0];   // [4,2048,1024]
  const float* Wqkv = (const float*)d_in[1];   // [1024,3072]
  const float* Wout = (const float*)d_in[2];   // [1024,1024]
  const float* bout = (const float*)d_in[3];   // [1024]
  float* out = (float*)d_out;                  // [4,2048,1024] fp32

  // workspace layout (bytes)
  char* ws = (char*)d_ws;
  short* xh    = (short*)(ws + 0);             //  16777216  fp16 x [8192][1024]
  short* WoutT = (short*)(ws + 16777216);      //   2097152  fp16 W_out^T [1024][1024]
  short* Wyv   = (short*)(ws + 18874368);      //   4194304  fp16 [M^T; Wvo^T] [2048][1024]
  short* y     = (short*)(ws + 23068672);      //  16777216  fp16 [8192][1024]
  short* VT    = (short*)(ws + 39845888);      //  16777216  bf16 v' [4][1024][2048]
  short* P     = (short*)(ws + 56623104);      //  33554432  bf16 [4][2048][2048]
  if (ws_size < 90177536) return;              // insufficient scratch -> visible failure

  cvt_f32_f16<<<8192, 256, 0, stream>>>(x, xh, 8388608 / 4);
  transpose_w<<<dim3(32, 32), 256, 0, stream>>>(Wout, 1024, 1024, WoutT);
  prep_gemm64<<<dim3(16, 32), 256, 0, stream>>>(Wqkv, WoutT, Wyv);

  // yv = xh @ Wyv^T  (y cols 0-1023 -> y; v' -> VT)           256 blocks (1/CU)
  gemm8p<0, 0, 8, 32><<<dim3(8, 32, 1), 512, 0, stream>>>(
      xh, 1024, 0, Wyv, 1024, 0, y, 1024, 0, 1024, VT);
  // P = exp(y @ xh^T)                                          256 blocks (1/CU)
  gemm8p<1, 0, 8, 8><<<dim3(8, 8, 4), 512, 0, stream>>>(
      y, 1024, 2048LL * 1024, xh, 1024, 2048LL * 1024,
      P, 2048, 2048LL * 2048, 1024, nullptr);
  // out = (P @ VT^T)/rowsum + bias  (rowsum fused via ones-MFMA)  512 blocks
  gemm_out<<<dim3(8, 16, 4), 256, 0, stream>>>(
      P, 2048, 2048LL * 2048, VT, 2048, 1024LL * 2048,
      out, 1024, 2048LL * 1024, 2048, bout);
}